// Round 10
// baseline (271.139 us; speedup 1.0000x reference)
//
#include <hip/hip_runtime.h>

#define NEGV (-1.0e9f)

typedef __bf16 bf16_t;
typedef __bf16 bf16x8 __attribute__((ext_vector_type(8)));
typedef __bf16 bf16x4 __attribute__((ext_vector_type(4)));
typedef float  f32x4  __attribute__((ext_vector_type(4)));

// async global->LDS, 16B per lane; LDS dest is wave-uniform base + lane*16
__device__ __forceinline__ void gld16(const void* g, void* l) {
    __builtin_amdgcn_global_load_lds(
        (const __attribute__((address_space(1))) void*)g,
        (__attribute__((address_space(3))) void*)l, 16, 0, 0);
}

// ---------------------------------------------------------------------------
// NT MFMA mainloop, double-buffered LDS, ONE barrier per K-step (round-6
// proven). C[128,128] tile = A[128,K] x B[128,K]^T (row-major, k-contiguous).
// 256 threads = 4 waves (2x2); each wave 64x64 via 4x4 mfma_f32_16x16x32_bf16.
// LDS XOR swizzle kills the 8-way ds_read_b128 bank conflict (global-side
// chunk permutation, since global_load_lds needs linear base+lane*16 dest).
// ---------------------------------------------------------------------------
__device__ __forceinline__ void nt_mainloop_db(
    const bf16_t* __restrict__ A, const bf16_t* __restrict__ B,
    int ldA, int ldB, int numKsteps,
    bf16_t* Atile, bf16_t* Btile,   // each 2 * 128*32
    int tid, f32x4 acc[4][4])
{
    const int w    = tid >> 6;
    const int lane = tid & 63;
    const int wm   = w & 1;
    const int wn   = w >> 1;
    const int srow = lane >> 2;
    const int skc  = ((lane & 3) ^ ((lane >> 3) & 3)) * 8;   // swizzled k-chunk
    const int quad = lane >> 4;
    const int l16  = lane & 15;
    const int sw   = (l16 >> 1) & 3;

    const bf16_t* ga0 = A + (size_t)((w * 2 + 0) * 16 + srow) * ldA + skc;
    const bf16_t* ga1 = A + (size_t)((w * 2 + 1) * 16 + srow) * ldA + skc;
    const bf16_t* gb0 = B + (size_t)((w * 2 + 0) * 16 + srow) * ldB + skc;
    const bf16_t* gb1 = B + (size_t)((w * 2 + 1) * 16 + srow) * ldB + skc;
    const int la0 = (w * 2 + 0) * 16 * 32;
    const int la1 = (w * 2 + 1) * 16 * 32;

    // prologue: stage tile 0 into buffer 0
    gld16(ga0, Atile + la0);
    gld16(ga1, Atile + la1);
    gld16(gb0, Btile + la0);
    gld16(gb1, Btile + la1);
    ga0 += 32; ga1 += 32; gb0 += 32; gb1 += 32;

    for (int kt = 0; kt < numKsteps; ++kt) {
        const int cur = (kt & 1) * (128 * 32);
        const int nxt = ((kt + 1) & 1) * (128 * 32);
        __syncthreads();   // drains own loads (compiler vmcnt) + cross-wave vis
        if (kt + 1 < numKsteps) {
            gld16(ga0, Atile + nxt + la0);
            gld16(ga1, Atile + nxt + la1);
            gld16(gb0, Btile + nxt + la0);
            gld16(gb1, Btile + nxt + la1);
            ga0 += 32; ga1 += 32; gb0 += 32; gb1 += 32;
        }
        bf16x8 af[4], bfr[4];
#pragma unroll
        for (int i = 0; i < 4; ++i)
            af[i] = *(const bf16x8*)&Atile[cur + (wm * 64 + i * 16 + l16) * 32 + ((quad ^ sw) * 8)];
#pragma unroll
        for (int j = 0; j < 4; ++j)
            bfr[j] = *(const bf16x8*)&Btile[cur + (wn * 64 + j * 16 + l16) * 32 + ((quad ^ sw) * 8)];
#pragma unroll
        for (int i = 0; i < 4; ++i)
#pragma unroll
            for (int j = 0; j < 4; ++j)
                acc[i][j] = __builtin_amdgcn_mfma_f32_16x16x32_bf16(af[i], bfr[j], acc[i][j], 0, 0, 0);
    }
}

// ---------------------------------------------------------------------------
__global__ __launch_bounds__(256)
void convert_x_kernel(const float* __restrict__ x, bf16_t* __restrict__ xb)
{
    const size_t i = ((size_t)blockIdx.x * 256 + threadIdx.x) * 8;
    float4 a = *(const float4*)&x[i];
    float4 b = *(const float4*)&x[i + 4];
    bf16x8 o;
    o[0] = (bf16_t)a.x; o[1] = (bf16_t)a.y; o[2] = (bf16_t)a.z; o[3] = (bf16_t)a.w;
    o[4] = (bf16_t)b.x; o[5] = (bf16_t)b.y; o[6] = (bf16_t)b.z; o[7] = (bf16_t)b.w;
    *(bf16x8*)&xb[i] = o;
}

// All three W [1024x1024] fp32 -> WT bf16 transposed, z selects matrix
__global__ __launch_bounds__(256)
void transpose_w_kernel(const float* __restrict__ W0, const float* __restrict__ W1,
                        const float* __restrict__ W2, bf16_t* __restrict__ WT)
{
    __shared__ float t[32][33];
    const float* W = (blockIdx.z == 0) ? W0 : (blockIdx.z == 1) ? W1 : W2;
    bf16_t* WTz = WT + (size_t)blockIdx.z * 1024 * 1024;
    const int k0 = blockIdx.y * 32, n0 = blockIdx.x * 32;
    const int r = threadIdx.x >> 3, c4 = (threadIdx.x & 7) * 4;
    float4 v = *(const float4*)&W[(size_t)(k0 + r) * 1024 + n0 + c4];
    t[r][c4 + 0] = v.x; t[r][c4 + 1] = v.y; t[r][c4 + 2] = v.z; t[r][c4 + 3] = v.w;
    __syncthreads();
    bf16x4 o;
#pragma unroll
    for (int j = 0; j < 4; ++j) o[j] = (bf16_t)t[c4 + j][r];
    *(bf16x4*)&WTz[(size_t)(n0 + r) * 1024 + k0 + c4] = o;
}

// ---------------------------------------------------------------------------
// Merged projection kernel, 1536 blocks:
//   blocks [0,1024):   QK tile — C[M,2048] = xb[M,1024] x WTqk^T + (bq|bk)
//   blocks [1024,1536): VT tile — VT[1024,8192] = WvT x xb^T + bv
// Both use the identical proven mainloop; only tile decode + epilogue differ.
// ---------------------------------------------------------------------------
__global__ __launch_bounds__(256)
void gemm_proj_kernel(const bf16_t* __restrict__ xb, const bf16_t* __restrict__ WT,
                      const float* __restrict__ bq, const float* __restrict__ bk,
                      const float* __restrict__ bv,
                      bf16_t* __restrict__ QK, bf16_t* __restrict__ VT)
{
    __shared__ bf16_t Atile[2 * 128 * 32];
    __shared__ bf16_t Btile[2 * 128 * 32];
    const int tid = threadIdx.x;
    const int bx = blockIdx.x;
    const int Kd = 1024;

    f32x4 acc[4][4];
#pragma unroll
    for (int i = 0; i < 4; ++i)
#pragma unroll
        for (int j = 0; j < 4; ++j) acc[i][j] = (f32x4)(0.0f);

    const int w = tid >> 6, lane = tid & 63;
    const int wm = w & 1, wn = w >> 1, quad = lane >> 4, l16 = lane & 15;

    if (bx < 1024) {
        // ---- QK tile: m0 over M=8192 (64 tiles), n0 over N=2048 (16 tiles)
        const int n0 = (bx & 15) * 128;
        const int m0 = (bx >> 4) * 128;
        nt_mainloop_db(xb + (size_t)m0 * Kd, WT + (size_t)n0 * Kd,
                       Kd, Kd, Kd / 32, Atile, Btile, tid, acc);
#pragma unroll
        for (int j = 0; j < 4; ++j) {
            const int col = n0 + wn * 64 + j * 16 + l16;
            const float bval = (col < 1024) ? bq[col] : bk[col - 1024];
#pragma unroll
            for (int i = 0; i < 4; ++i) {
#pragma unroll
                for (int r = 0; r < 4; ++r) {
                    const int row = m0 + wm * 64 + i * 16 + quad * 4 + r;
                    QK[(size_t)row * 2048 + col] = (bf16_t)(acc[i][j][r] + bval);
                }
            }
        }
    } else {
        // ---- VT tile: m0 over D=1024 (8 tiles), n0 over M=8192 (64 tiles)
        const int t = bx - 1024;
        const int m0 = (t & 7) * 128;
        const int n0 = (t >> 3) * 128;
        const bf16_t* WvT = WT + (size_t)2 * 1024 * 1024;
        nt_mainloop_db(WvT + (size_t)m0 * Kd, xb + (size_t)n0 * Kd,
                       Kd, Kd, Kd / 32, Atile, Btile, tid, acc);
#pragma unroll
        for (int i = 0; i < 4; ++i) {
#pragma unroll
            for (int r = 0; r < 4; ++r) {
                const int row = m0 + wm * 64 + i * 16 + quad * 4 + r;   // d
                const float bval = bv[row];
#pragma unroll
                for (int j = 0; j < 4; ++j) {
                    const int col = n0 + wn * 64 + j * 16 + l16;        // b*L+l
                    VT[(size_t)row * 8192 + col] = (bf16_t)(acc[i][j][r] + bval);
                }
            }
        }
    }
}

// ---------------------------------------------------------------------------
// Scores, triangular-only launch: blockIdx.x in [0,136) -> (it,jt), jt<=it.
// Masks applied in reference order (fp32 -1e9 adds) in the epilogue.
// ---------------------------------------------------------------------------
__global__ __launch_bounds__(256)
void scores_mfma_kernel(const bf16_t* __restrict__ Q, const bf16_t* __restrict__ K,
                        int ldq, const int* __restrict__ lengths,
                        float* __restrict__ S, int L, int Dd, float alpha)
{
    const int b = blockIdx.z;
    const int len = lengths[b];
    int it = (int)((sqrtf(8.0f * blockIdx.x + 1.0f) - 1.0f) * 0.5f);
    while ((it + 1) * (it + 2) / 2 <= (int)blockIdx.x) ++it;
    while (it * (it + 1) / 2 > (int)blockIdx.x) --it;
    const int jt = blockIdx.x - it * (it + 1) / 2;
    const int m0 = it * 128, n0 = jt * 128;
    float* Sb = S + (size_t)b * L * L;
    const int tid = threadIdx.x;

    __shared__ bf16_t Atile[2 * 128 * 32];
    __shared__ bf16_t Btile[2 * 128 * 32];
    f32x4 acc[4][4];
#pragma unroll
    for (int i = 0; i < 4; ++i)
#pragma unroll
        for (int j = 0; j < 4; ++j) acc[i][j] = (f32x4)(0.0f);

    const bf16_t* Qb = Q + (size_t)b * L * ldq + (size_t)m0 * ldq;
    const bf16_t* Kb = K + (size_t)b * L * ldq + (size_t)n0 * ldq;
    nt_mainloop_db(Qb, Kb, ldq, ldq, Dd / 32, Atile, Btile, tid, acc);

    const int w = tid >> 6, lane = tid & 63;
    const int wm = w & 1, wn = w >> 1, quad = lane >> 4, l16 = lane & 15;
#pragma unroll
    for (int i = 0; i < 4; ++i) {
#pragma unroll
        for (int j = 0; j < 4; ++j) {
            const int col = n0 + wn * 64 + j * 16 + l16;
#pragma unroll
            for (int r = 0; r < 4; ++r) {
                const int row = m0 + wm * 64 + i * 16 + quad * 4 + r;
                float s = acc[i][j][r] * alpha;
                if (col > row) s += NEGV;                 // causal first
                if (row >= len || col >= len) s += NEGV;  // then length mask
                Sb[(size_t)row * L + col] = s;
            }
        }
    }
}

// ---------------------------------------------------------------------------
// Row softmax, causally bounded: reads S[0,bound), writes P[0,bound) bf16,
// bound = round_up(i+1,128). PV's k-limit never reads past bound.
// ---------------------------------------------------------------------------
__global__ __launch_bounds__(256)
void softmax_kernel(const float* __restrict__ S, bf16_t* __restrict__ P,
                    int L, int ldp)
{
    __shared__ float red[8];
    const int i = blockIdx.x;
    const int bound = ((i >> 7) + 1) << 7;
    const float* row = S + ((size_t)blockIdx.y * L + i) * L;
    bf16_t* prow = P + ((size_t)blockIdx.y * L + i) * ldp;
    const int t = threadIdx.x;
    const int w = t >> 6, lane = t & 63;
    const int j8 = t * 8;
    const bool act = j8 < bound;

    float v[8];
    float m = -3.0e38f;
    if (act) {
        float4 a = *(const float4*)&row[j8];
        float4 b = *(const float4*)&row[j8 + 4];
        v[0] = a.x; v[1] = a.y; v[2] = a.z; v[3] = a.w;
        v[4] = b.x; v[5] = b.y; v[6] = b.z; v[7] = b.w;
#pragma unroll
        for (int j = 0; j < 8; ++j) m = fmaxf(m, v[j]);
    }
#pragma unroll
    for (int off = 32; off > 0; off >>= 1) m = fmaxf(m, __shfl_down(m, off, 64));
    if (lane == 0) red[w] = m;
    __syncthreads();
    m = fmaxf(fmaxf(red[0], red[1]), fmaxf(red[2], red[3]));

    float s = 0.f;
    if (act) {
#pragma unroll
        for (int j = 0; j < 8; ++j) {
            v[j] = __expf(v[j] - m);
            s += v[j];
        }
    }
#pragma unroll
    for (int off = 32; off > 0; off >>= 1) s += __shfl_down(s, off, 64);
    if (lane == 0) red[4 + w] = s;
    __syncthreads();
    s = red[4] + red[5] + red[6] + red[7];

    if (act) {
        const float inv = 1.0f / s;
        bf16x8 o;
#pragma unroll
        for (int j = 0; j < 8; ++j) o[j] = (bf16_t)(v[j] * inv);
        *(bf16x8*)&prow[j8] = o;
    }
}

// ---------------------------------------------------------------------------
// PV: O[b][L,D] fp32 = P[b][L,L] x V^T (VT layout [d][b][l], ld 8192),
// causal k-limit, heavy tiles dispatched first.
// ---------------------------------------------------------------------------
__global__ __launch_bounds__(256)
void pv_mfma_kernel(const bf16_t* __restrict__ P, int ldp,
                    const bf16_t* __restrict__ VT, int ldv,
                    float* __restrict__ O, int L, int Dd)
{
    __shared__ bf16_t Atile[2 * 128 * 32];
    __shared__ bf16_t Btile[2 * 128 * 32];
    const int b = blockIdx.z;
    const int mt = gridDim.y - 1 - blockIdx.y;   // heavy first
    const int m0 = mt * 128, n0 = blockIdx.x * 128;
    const int tid = threadIdx.x;

    f32x4 acc[4][4];
#pragma unroll
    for (int i = 0; i < 4; ++i)
#pragma unroll
        for (int j = 0; j < 4; ++j) acc[i][j] = (f32x4)(0.0f);

    const int ksteps = (m0 + 128) / 32;   // P[i][j]==0 for j>i
    const bf16_t* Pb = P + (size_t)b * L * ldp + (size_t)m0 * ldp;
    const bf16_t* Vb = VT + (size_t)b * L + (size_t)n0 * ldv;
    nt_mainloop_db(Pb, Vb, ldp, ldv, ksteps, Atile, Btile, tid, acc);

    float* Ob = O + (size_t)b * L * Dd;
    const int w = tid >> 6, lane = tid & 63;
    const int wm = w & 1, wn = w >> 1, quad = lane >> 4, l16 = lane & 15;
#pragma unroll
    for (int i = 0; i < 4; ++i) {
#pragma unroll
        for (int j = 0; j < 4; ++j) {
            const int col = n0 + wn * 64 + j * 16 + l16;
#pragma unroll
            for (int r = 0; r < 4; ++r) {
                const int row = m0 + wm * 64 + i * 16 + quad * 4 + r;
                Ob[(size_t)row * Dd + col] = acc[i][j][r];
            }
        }
    }
}

// ---------------------------------------------------------------------------
extern "C" void kernel_launch(void* const* d_in, const int* in_sizes, int n_in,
                              void* d_out, int out_size, void* d_ws, size_t ws_size,
                              hipStream_t stream)
{
    const float* x  = (const float*)d_in[0];
    const float* Wq = (const float*)d_in[1];
    const float* bq = (const float*)d_in[2];
    const float* Wk = (const float*)d_in[3];
    const float* bk = (const float*)d_in[4];
    const float* Wv = (const float*)d_in[5];
    const float* bv = (const float*)d_in[6];
    const int*  len = (const int*)d_in[7];
    float* out = (float*)d_out;

    const int B = 4, L = 2048, D = 1024;
    const int M = B * L;     // 8192
    const int N2 = 2 * D;    // 2048

    // Workspace (134 MB, same layout as the proven round-6 run):
    //  xb [8192][1024] bf16 = 16 MB
    //  WT [3072][1024] bf16 = 6 MB   (Wq^T | Wk^T | Wv^T)
    //  QK [8192][2048] bf16 = 32 MB  (cols 0:Q 1024:K; rows reused as P, ld 2048)
    //  VT [1024][8192] bf16 = 16 MB  (layout [d][b][l])
    //  S  [4][2048][2048] fp32 = 64 MB (lower-triangular tiles only)
    bf16_t* xb = (bf16_t*)d_ws;
    bf16_t* WT = xb + (size_t)M * D;
    bf16_t* QK = WT + (size_t)3 * D * D;
    bf16_t* VT = QK + (size_t)M * N2;
    float*  S  = (float*)(VT + (size_t)D * M);
    bf16_t* P  = QK;   // alias: Q,K dead after scores; ld = 2048

    // 1) x -> bf16
    convert_x_kernel<<<(M * D) / 2048, 256, 0, stream>>>(x, xb);

    // 2) all W transposes in one launch
    transpose_w_kernel<<<dim3(32, 32, 3), 256, 0, stream>>>(Wq, Wk, Wv, WT);

    // 3) merged QK + VT projections (1536 blocks = 6/CU)
    gemm_proj_kernel<<<dim3(1536), 256, 0, stream>>>(
        xb, WT, bq, bk, bv, QK, VT);

    // 4) scores, triangular tiles only
    scores_mfma_kernel<<<dim3(136, 1, B), 256, 0, stream>>>(
        QK, QK + 1024, N2, len, S, L, D, 0.03125f);

    // 5) bounded softmax -> P (aliased over QK rows)
    softmax_kernel<<<dim3(L, B), 256, 0, stream>>>(S, P, L, N2);

    // 6) O = P @ V, causal k-limit, heavy tiles first
    pv_mfma_kernel<<<dim3(D / 128, L / 128, B), 256, 0, stream>>>(
        P, N2, VT, M, out, L, D);
}